// Round 1
// baseline (770.312 us; speedup 1.0000x reference)
//
#include <hip/hip_runtime.h>

namespace {

constexpr int kH  = 1024;
constexpr int kW  = 1024;
constexpr int kHW = kH * kW;
constexpr int kSH = 68;          // int(1023/16)+1+2*2
constexpr int kSW = 68;
constexpr int kDMAX = 8;         // features uniform [0,1): delta<1 -> depth <= 8
constexpr int kTMAX = kSH * kSW * kDMAX * kDMAX * kDMAX;   // 2,367,488 cells

// ---- header layout in d_ws (uint words) ----
// [0..2]  min bits per feature channel (positive floats: bit order == value order)
// [3..5]  max bits per feature channel
// [8]  dr  [9] dg  [10] db  [11] T = kSH*kSW*dr*dg*db

__global__ void init_hdr_kernel(unsigned* hdr) {
    int t = threadIdx.x;
    if (t < 3) hdr[t] = 0x7f800000u;      // +inf
    else if (t < 6) hdr[t] = 0u;          // values are >= 0
}

__global__ void minmax_kernel(const float* __restrict__ feat, unsigned* hdr) {
    float mn[3] = {1e30f, 1e30f, 1e30f};
    float mx[3] = {-1e30f, -1e30f, -1e30f};
    int tid = blockIdx.x * blockDim.x + threadIdx.x;
    int stride = gridDim.x * blockDim.x;
    for (int p = tid; p < kHW; p += stride) {
        #pragma unroll
        for (int c = 0; c < 3; ++c) {
            float v = feat[p * 3 + c];
            mn[c] = fminf(mn[c], v);
            mx[c] = fmaxf(mx[c], v);
        }
    }
    #pragma unroll
    for (int off = 32; off > 0; off >>= 1) {
        #pragma unroll
        for (int c = 0; c < 3; ++c) {
            mn[c] = fminf(mn[c], __shfl_down(mn[c], off, 64));
            mx[c] = fmaxf(mx[c], __shfl_down(mx[c], off, 64));
        }
    }
    if ((threadIdx.x & 63) == 0) {
        #pragma unroll
        for (int c = 0; c < 3; ++c) {
            atomicMin(&hdr[c],     __float_as_uint(mn[c]));
            atomicMax(&hdr[3 + c], __float_as_uint(mx[c]));
        }
    }
}

__global__ void params_kernel(unsigned* hdr) {
    if (threadIdx.x == 0 && blockIdx.x == 0) {
        int* ip = (int*)(hdr + 8);
        int d[3];
        for (int c = 0; c < 3; ++c) {
            float mnf = __uint_as_float(hdr[c]);
            float mxf = __uint_as_float(hdr[3 + c]);
            float delta = mxf - mnf;                       // fp32 sub, like numpy
            int depth = (int)((double)delta / 0.25) + 1 + 4; // int(float(delta)/0.25)+1+2*PAD_Z
            if (depth > kDMAX) depth = kDMAX;
            if (depth < 1) depth = 1;
            d[c] = depth;
        }
        ip[0] = d[0]; ip[1] = d[1]; ip[2] = d[2];
        ip[3] = kSH * kSW * d[0] * d[1] * d[2];
    }
}

__global__ void splat_kernel(const float* __restrict__ feat,
                             const float* __restrict__ inp,
                             const unsigned* __restrict__ hdr,
                             float* __restrict__ grid) {
    int p = blockIdx.x * blockDim.x + threadIdx.x;
    if (p >= kHW) return;
    const int* ip = (const int*)(hdr + 8);
    int dr = ip[0], dg = ip[1], db = ip[2], T = ip[3];
    int y = p / kW, x = p % kW;
    // splat coords: int(coord/16 + 0.5) + 2  (values >= 0 so trunc == floor)
    int sy = (int)((float)y * 0.0625f + 0.5f) + 2;
    int sx = (int)((float)x * 0.0625f + 0.5f) + 2;
    float v0 = feat[p * 3 + 0] - __uint_as_float(hdr[0]);
    float v1 = feat[p * 3 + 1] - __uint_as_float(hdr[1]);
    float v2 = feat[p * 3 + 2] - __uint_as_float(hdr[2]);
    int sr = (int)(v0 * 4.0f + 0.5f) + 2;   // /0.25 == *4, exact
    int sg = (int)(v1 * 4.0f + 0.5f) + 2;
    int sb = (int)(v2 * 4.0f + 0.5f) + 2;
    int coord = (((sy * kSW + sx) * dr + sr) * dg + sg) * db + sb;
    atomicAdd(&grid[0 * T + coord], inp[p * 3 + 0]);
    atomicAdd(&grid[1 * T + coord], inp[p * 3 + 1]);
    atomicAdd(&grid[2 * T + coord], inp[p * 3 + 2]);
}

// One blur pass along `axis` replicating _convn semantics:
// interior cells along `axis` get (src[i-1]+src[i+1]+2*src[i])/4; boundary
// cells along `axis` are NOT written (dst retains its prior value).
__global__ void blur_kernel(float* __restrict__ dst,
                            const float* __restrict__ src,
                            const unsigned* __restrict__ hdr,
                            int axis) {
    const int* ip = (const int*)(hdr + 8);
    int dr = ip[0], dg = ip[1], db = ip[2], T = ip[3];
    int idx = blockIdx.x * blockDim.x + threadIdx.x;
    if (idx >= 3 * T) return;
    int cell = idx % T;
    int n, s;
    int s3 = db, s2 = dg * db, s1 = dr * s2, s0 = kSW * s1;
    switch (axis) {
        case 0: n = kSH; s = s0; break;
        case 1: n = kSW; s = s1; break;
        case 2: n = dr;  s = s2; break;
        case 3: n = dg;  s = s3; break;
        default: n = db; s = 1;  break;
    }
    int i = (cell / s) % n;
    if (i > 0 && i < n - 1) {
        dst[idx] = ((src[idx - s] + src[idx + s]) + 2.0f * src[idx]) * 0.25f;
    }
}

__global__ void slice_kernel(const float* __restrict__ feat,
                             const unsigned* __restrict__ hdr,
                             const float* __restrict__ grid,
                             float* __restrict__ out) {
    int p = blockIdx.x * blockDim.x + threadIdx.x;
    if (p >= kHW) return;
    const int* ip = (const int*)(hdr + 8);
    int dr = ip[0], dg = ip[1], db = ip[2], T = ip[3];
    int y = p / kW, x = p % kW;

    float fy = (float)y * 0.0625f + 2.0f;
    float fx = (float)x * 0.0625f + 2.0f;
    int yi = (int)fy; yi = yi < 0 ? 0 : (yi > kSH - 1 ? kSH - 1 : yi);
    int yi2 = yi + 1 > kSH - 1 ? kSH - 1 : yi + 1;
    float ya = fy - (float)yi;
    int xi = (int)fx; xi = xi < 0 ? 0 : (xi > kSW - 1 ? kSW - 1 : xi);
    int xi2 = xi + 1 > kSW - 1 ? kSW - 1 : xi + 1;
    float xa = fx - (float)xi;

    int d3[3] = {dr, dg, db};
    int li[3], ri[3];
    float al[3];
    #pragma unroll
    for (int c = 0; c < 3; ++c) {
        float v0 = feat[p * 3 + c] - __uint_as_float(hdr[c]);
        float sv = v0 * 4.0f + 2.0f;
        int l = (int)sv;
        int dm = d3[c] - 1;
        l = l < 0 ? 0 : (l > dm ? dm : l);
        int r = l + 1 > dm ? dm : l + 1;
        li[c] = l; ri[c] = r; al[c] = sv - (float)l;
    }

    int ys[2] = {yi, yi2};   float wy[2] = {1.0f - ya, ya};
    int xs[2] = {xi, xi2};   float wx[2] = {1.0f - xa, xa};
    int rs[2] = {li[0], ri[0]}; float wr[2] = {1.0f - al[0], al[0]};
    int gs[2] = {li[1], ri[1]}; float wg[2] = {1.0f - al[1], al[1]};
    int bs[2] = {li[2], ri[2]}; float wb[2] = {1.0f - al[2], al[2]};

    float acc0 = 0.0f, acc1 = 0.0f, acc2 = 0.0f;
    #pragma unroll
    for (int cy = 0; cy < 2; ++cy)
    #pragma unroll
    for (int cx = 0; cx < 2; ++cx)
    #pragma unroll
    for (int cr = 0; cr < 2; ++cr)
    #pragma unroll
    for (int cg = 0; cg < 2; ++cg)
    #pragma unroll
    for (int cb = 0; cb < 2; ++cb) {
        int coord = (((ys[cy] * kSW + xs[cx]) * dr + rs[cr]) * dg + gs[cg]) * db + bs[cb];
        float w = (((wy[cy] * wx[cx]) * wr[cr]) * wg[cg]) * wb[cb];
        acc0 += w * grid[coord];
        acc1 += w * grid[T + coord];
        acc2 += w * grid[2 * T + coord];
    }
    out[p * 3 + 0] = acc0;
    out[p * 3 + 1] = acc1;
    out[p * 3 + 2] = acc2;
}

}  // namespace

extern "C" void kernel_launch(void* const* d_in, const int* in_sizes, int n_in,
                              void* d_out, int out_size, void* d_ws, size_t ws_size,
                              hipStream_t stream) {
    const float* feat = (const float*)d_in[0];
    const float* inp  = (const float*)d_in[1];
    float* out = (float*)d_out;

    unsigned* hdr = (unsigned*)d_ws;
    float* gridA = (float*)((char*)d_ws + 256);        // splat -> iter2 data -> result
    float* gridB = gridA + 3 * (size_t)kTMAX;          // iter1 data

    // zero both grids (ws is poisoned 0xAA before every timed call)
    hipMemsetAsync(gridA, 0, 2 * 3 * (size_t)kTMAX * sizeof(float), stream);

    init_hdr_kernel<<<1, 64, 0, stream>>>(hdr);
    minmax_kernel<<<1024, 256, 0, stream>>>(feat, hdr);
    params_kernel<<<1, 1, 0, stream>>>(hdr);

    splat_kernel<<<(kHW + 255) / 256, 256, 0, stream>>>(feat, inp, hdr, gridA);

    int blurBlocks = (3 * kTMAX + 255) / 256;
    // outer iter 1: buffer = gridA (splat, untouched), data = gridB (zeros)
    for (int axis = 0; axis < 5; ++axis)
        blur_kernel<<<blurBlocks, 256, 0, stream>>>(gridB, gridA, hdr, axis);
    // outer iter 2: buffer = gridB (iter1 result), data = gridA (original splat)
    for (int axis = 0; axis < 5; ++axis)
        blur_kernel<<<blurBlocks, 256, 0, stream>>>(gridA, gridB, hdr, axis);

    slice_kernel<<<(kHW + 255) / 256, 256, 0, stream>>>(feat, hdr, gridA, out);
}

// Round 2
// 323.256 us; speedup vs baseline: 2.3830x; 2.3830x over previous
//
#include <hip/hip_runtime.h>

namespace {

constexpr int kH  = 1024;
constexpr int kW  = 1024;
constexpr int kHW = kH * kW;
constexpr int kSH = 68;           // int(1023/16)+1+2*2
constexpr int kSW = 68;
constexpr int kD  = 8;            // max depth; features uniform [0,1) -> depth <= 8
constexpr int kT3 = kSH * kSW * kD * kD * kD;   // 2,367,488 cells per channel
// fixed strides (floats) inside one channel grid [68][68][8][8][8]
constexpr int kSG = 8;
constexpr int kSR = 64;
constexpr int kSX = 512;
constexpr int kSY = 512 * 68;     // 34816
constexpr int kLines = 3 * kSH * kSW * kD * kD; // 887,808 b-lines of 8 cells

// ---- header layout in d_ws (uint words) ----
// [0..2] min bits per channel   [3..5] max bits per channel
// [8] dr [9] dg [10] db

__global__ void init_hdr_kernel(unsigned* hdr) {
    int t = threadIdx.x;
    if (t < 3) hdr[t] = 0x7f800000u;      // +inf (values >= 0, bit order == value order)
    else if (t < 6) hdr[t] = 0u;
}

__global__ void minmax_kernel(const float* __restrict__ feat, unsigned* hdr) {
    float mn[3] = {1e30f, 1e30f, 1e30f};
    float mx[3] = {-1e30f, -1e30f, -1e30f};
    int tid = blockIdx.x * blockDim.x + threadIdx.x;
    int stride = gridDim.x * blockDim.x;
    for (int p = tid; p < kHW; p += stride) {
        #pragma unroll
        for (int c = 0; c < 3; ++c) {
            float v = feat[p * 3 + c];
            mn[c] = fminf(mn[c], v);
            mx[c] = fmaxf(mx[c], v);
        }
    }
    #pragma unroll
    for (int off = 32; off > 0; off >>= 1) {
        #pragma unroll
        for (int c = 0; c < 3; ++c) {
            mn[c] = fminf(mn[c], __shfl_down(mn[c], off, 64));
            mx[c] = fmaxf(mx[c], __shfl_down(mx[c], off, 64));
        }
    }
    __shared__ float smn[4][3], smx[4][3];
    int wave = threadIdx.x >> 6;
    if ((threadIdx.x & 63) == 0) {
        #pragma unroll
        for (int c = 0; c < 3; ++c) { smn[wave][c] = mn[c]; smx[wave][c] = mx[c]; }
    }
    __syncthreads();
    if (threadIdx.x == 0) {
        #pragma unroll
        for (int c = 0; c < 3; ++c) {
            float bmn = fminf(fminf(smn[0][c], smn[1][c]), fminf(smn[2][c], smn[3][c]));
            float bmx = fmaxf(fmaxf(smx[0][c], smx[1][c]), fmaxf(smx[2][c], smx[3][c]));
            atomicMin(&hdr[c],     __float_as_uint(bmn));
            atomicMax(&hdr[3 + c], __float_as_uint(bmx));
        }
    }
}

__global__ void params_kernel(unsigned* hdr) {
    if (threadIdx.x == 0 && blockIdx.x == 0) {
        int* ip = (int*)(hdr + 8);
        for (int c = 0; c < 3; ++c) {
            float mnf = __uint_as_float(hdr[c]);
            float mxf = __uint_as_float(hdr[3 + c]);
            float delta = mxf - mnf;                        // fp32 sub, like numpy
            int depth = (int)((double)delta / 0.25) + 1 + 4;
            if (depth > kD) depth = kD;
            if (depth < 1) depth = 1;
            ip[c] = depth;
        }
    }
}

__global__ void splat_kernel(const float* __restrict__ feat,
                             const float* __restrict__ inp,
                             const unsigned* __restrict__ hdr,
                             float* __restrict__ grid) {
    int p = blockIdx.x * blockDim.x + threadIdx.x;
    if (p >= kHW) return;
    int y = p >> 10, x = p & 1023;
    int sy = ((y + 8) >> 4) + 2;          // == int(y/16 + 0.5) + 2 (exact)
    int sx = ((x + 8) >> 4) + 2;
    float v0 = feat[p * 3 + 0] - __uint_as_float(hdr[0]);
    float v1 = feat[p * 3 + 1] - __uint_as_float(hdr[1]);
    float v2 = feat[p * 3 + 2] - __uint_as_float(hdr[2]);
    int sr = (int)(v0 * 4.0f + 0.5f) + 2;  // /0.25 == *4 exact
    int sg = (int)(v1 * 4.0f + 0.5f) + 2;
    int sb = (int)(v2 * 4.0f + 0.5f) + 2;
    int coord = ((sy * kSW + sx) << 9) + (sr << 6) + (sg << 3) + sb;
    atomicAdd(&grid[coord],            inp[p * 3 + 0]);
    atomicAdd(&grid[kT3 + coord],      inp[p * 3 + 1]);
    atomicAdd(&grid[2 * kT3 + coord],  inp[p * 3 + 2]);
}

// One fused _convn outer-iteration. Key insight: inside the reference's inner
// loop, `buffer` is never modified — every axis-blur reads the SAME source, and
// writes interior slices over `data` in axis order y,x,r,g,b. Last write wins:
//   b interior       -> blur_b(src)
//   else g interior  -> blur_g(src)
//   else r interior  -> blur_r(src)
//   else x interior  -> blur_x(src)
//   else y interior  -> blur_y(src)
//   else             -> dst retains its prior value (iter1: zeros, iter2: splat)
// One thread per contiguous 8-cell b-line.
__global__ void blur_fused_kernel(float* __restrict__ dst,
                                  const float* __restrict__ src,
                                  const unsigned* __restrict__ hdr) {
    int line = blockIdx.x * blockDim.x + threadIdx.x;
    if (line >= kLines) return;
    const int* ip = (const int*)(hdr + 8);
    int dr = ip[0], dg = ip[1], db = ip[2];

    int g = line & 7;
    int r = (line >> 3) & 7;
    int rest = line >> 6;           // ch*68*68 + y*68 + x
    int x = rest % 68;
    int yc = rest / 68;             // ch*68 + y
    int y = yc % 68;

    long base = (long)line * 8;
    const float4* s4 = (const float4*)(src + base);
    float4 lo = s4[0], hi = s4[1];
    float v[8] = {lo.x, lo.y, lo.z, lo.w, hi.x, hi.y, hi.z, hi.w};

    bool gInt = (g >= 1) && (g <= dg - 2);
    bool rInt = (r >= 1) && (r <= dr - 2);
    bool xInt = (x >= 1) && (x <= kSW - 2);
    bool yInt = (y >= 1) && (y <= kSH - 2);
    int fs = gInt ? kSG : (rInt ? kSR : (xInt ? kSX : (yInt ? kSY : 0)));

    float out[8];
    bool  wr[8];
    #pragma unroll
    for (int b = 0; b < 8; ++b) {
        if (b >= 1 && b <= db - 2) {
            out[b] = ((v[b - 1] + v[b + 1]) + 2.0f * v[b]) * 0.25f;
            wr[b] = true;
        } else if (fs != 0) {
            out[b] = ((src[base + b - fs] + src[base + b + fs]) + 2.0f * v[b]) * 0.25f;
            wr[b] = true;
        } else {
            out[b] = 0.0f;
            wr[b] = false;
        }
    }
    bool all8 = wr[0] && wr[1] && wr[2] && wr[3] && wr[4] && wr[5] && wr[6] && wr[7];
    if (all8) {
        float4* d4 = (float4*)(dst + base);
        d4[0] = make_float4(out[0], out[1], out[2], out[3]);
        d4[1] = make_float4(out[4], out[5], out[6], out[7]);
    } else {
        #pragma unroll
        for (int b = 0; b < 8; ++b)
            if (wr[b]) dst[base + b] = out[b];
    }
}

__global__ void slice_kernel(const float* __restrict__ feat,
                             const unsigned* __restrict__ hdr,
                             const float* __restrict__ grid,
                             float* __restrict__ out) {
    int p = blockIdx.x * blockDim.x + threadIdx.x;
    if (p >= kHW) return;
    const int* ip = (const int*)(hdr + 8);
    int d3[3] = {ip[0], ip[1], ip[2]};
    int y = p >> 10, x = p & 1023;

    int yi = (y >> 4) + 2;                 // int(y/16 + 2), never clamps (<=65)
    int xi = (x >> 4) + 2;
    float ya = (float)(y & 15) * 0.0625f;  // exact fractional part
    float xa = (float)(x & 15) * 0.0625f;

    int li[3], ri[3];
    float al[3];
    #pragma unroll
    for (int c = 0; c < 3; ++c) {
        float v0 = feat[p * 3 + c] - __uint_as_float(hdr[c]);
        float sv = v0 * 4.0f + 2.0f;
        int l = (int)sv;
        int dm = d3[c] - 1;
        l = l < 0 ? 0 : (l > dm ? dm : l);
        int rr = l + 1 > dm ? dm : l + 1;
        li[c] = l; ri[c] = rr; al[c] = sv - (float)l;
    }

    // spatial part: 4 corners
    int spi[4]; float spw[4];
    {
        int ys[2] = {yi, yi + 1};  float wy[2] = {1.0f - ya, ya};
        int xs[2] = {xi, xi + 1};  float wx[2] = {1.0f - xa, xa};
        #pragma unroll
        for (int cy = 0; cy < 2; ++cy)
        #pragma unroll
        for (int cx = 0; cx < 2; ++cx) {
            spi[cy * 2 + cx] = (ys[cy] * kSW + xs[cx]) << 9;
            spw[cy * 2 + cx] = wy[cy] * wx[cx];
        }
    }
    // color part: 8 corners
    int cpi[8]; float cpw[8];
    {
        int rs[2] = {li[0], ri[0]}; float wrr[2] = {1.0f - al[0], al[0]};
        int gs[2] = {li[1], ri[1]}; float wgg[2] = {1.0f - al[1], al[1]};
        int bs[2] = {li[2], ri[2]}; float wbb[2] = {1.0f - al[2], al[2]};
        #pragma unroll
        for (int cr = 0; cr < 2; ++cr)
        #pragma unroll
        for (int cg = 0; cg < 2; ++cg)
        #pragma unroll
        for (int cb = 0; cb < 2; ++cb) {
            int k = (cr * 2 + cg) * 2 + cb;
            cpi[k] = (rs[cr] << 6) + (gs[cg] << 3) + bs[cb];
            cpw[k] = (wrr[cr] * wgg[cg]) * wbb[cb];
        }
    }

    float acc0 = 0.0f, acc1 = 0.0f, acc2 = 0.0f;
    #pragma unroll
    for (int k = 0; k < 4; ++k) {
        #pragma unroll
        for (int j = 0; j < 8; ++j) {
            int c = spi[k] + cpi[j];
            float w = spw[k] * cpw[j];
            acc0 += w * grid[c];
            acc1 += w * grid[kT3 + c];
            acc2 += w * grid[2 * kT3 + c];
        }
    }
    out[p * 3 + 0] = acc0;
    out[p * 3 + 1] = acc1;
    out[p * 3 + 2] = acc2;
}

}  // namespace

extern "C" void kernel_launch(void* const* d_in, const int* in_sizes, int n_in,
                              void* d_out, int out_size, void* d_ws, size_t ws_size,
                              hipStream_t stream) {
    const float* feat = (const float*)d_in[0];
    const float* inp  = (const float*)d_in[1];
    float* out = (float*)d_out;

    unsigned* hdr = (unsigned*)d_ws;
    float* gridA = (float*)((char*)d_ws + 256);        // splat -> iter2 result
    float* gridB = gridA + 3 * (size_t)kT3;            // iter1 result

    hipMemsetAsync(gridA, 0, 2 * 3 * (size_t)kT3 * sizeof(float), stream);

    init_hdr_kernel<<<1, 64, 0, stream>>>(hdr);
    minmax_kernel<<<256, 256, 0, stream>>>(feat, hdr);
    params_kernel<<<1, 1, 0, stream>>>(hdr);

    splat_kernel<<<(kHW + 255) / 256, 256, 0, stream>>>(feat, inp, hdr, gridA);

    int blurBlocks = (kLines + 255) / 256;
    // _convn outer iter 1: src = gridA (splat), dst = gridB (zeros)
    blur_fused_kernel<<<blurBlocks, 256, 0, stream>>>(gridB, gridA, hdr);
    // _convn outer iter 2: src = gridB, dst = gridA (holds original splat = `data`)
    blur_fused_kernel<<<blurBlocks, 256, 0, stream>>>(gridA, gridB, hdr);

    slice_kernel<<<(kHW + 255) / 256, 256, 0, stream>>>(feat, hdr, gridA, out);
}

// Round 3
// 242.181 us; speedup vs baseline: 3.1807x; 1.3348x over previous
//
#include <hip/hip_runtime.h>

namespace {

constexpr int kH  = 1024;
constexpr int kW  = 1024;
constexpr int kHW = kH * kW;
constexpr int kSH = 68;           // int(1023/16)+1+2*2
constexpr int kSW = 68;
constexpr int kD  = 8;            // max depth; features uniform [0,1) -> depth <= 8
constexpr int kT3 = kSH * kSW * kD * kD * kD;   // 2,367,488 cells per channel
// fixed strides (floats) inside one channel grid [68][68][8][8][8]
constexpr int kSG = 8;
constexpr int kSR = 64;
constexpr int kSX = 512;
constexpr int kSY = 512 * 68;     // 34816
constexpr int kLines = 3 * kSH * kSW * kD * kD; // 887,808 b-lines of 8 cells

// ---- header layout in d_ws (uint words) ----
// [0..2] min bits per channel   [3..5] max bits per channel
// [8] dr [9] dg [10] db

__global__ void init_hdr_kernel(unsigned* hdr) {
    int t = threadIdx.x;
    if (t < 3) hdr[t] = 0x7f800000u;      // +inf (values >= 0, bit order == value order)
    else if (t < 6) hdr[t] = 0u;
}

__global__ void minmax_kernel(const float* __restrict__ feat, unsigned* hdr) {
    float mn[3] = {1e30f, 1e30f, 1e30f};
    float mx[3] = {-1e30f, -1e30f, -1e30f};
    int tid = blockIdx.x * blockDim.x + threadIdx.x;
    int stride = gridDim.x * blockDim.x;
    for (int p = tid; p < kHW; p += stride) {
        #pragma unroll
        for (int c = 0; c < 3; ++c) {
            float v = feat[p * 3 + c];
            mn[c] = fminf(mn[c], v);
            mx[c] = fmaxf(mx[c], v);
        }
    }
    #pragma unroll
    for (int off = 32; off > 0; off >>= 1) {
        #pragma unroll
        for (int c = 0; c < 3; ++c) {
            mn[c] = fminf(mn[c], __shfl_down(mn[c], off, 64));
            mx[c] = fmaxf(mx[c], __shfl_down(mx[c], off, 64));
        }
    }
    __shared__ float smn[4][3], smx[4][3];
    int wave = threadIdx.x >> 6;
    if ((threadIdx.x & 63) == 0) {
        #pragma unroll
        for (int c = 0; c < 3; ++c) { smn[wave][c] = mn[c]; smx[wave][c] = mx[c]; }
    }
    __syncthreads();
    if (threadIdx.x == 0) {
        #pragma unroll
        for (int c = 0; c < 3; ++c) {
            float bmn = fminf(fminf(smn[0][c], smn[1][c]), fminf(smn[2][c], smn[3][c]));
            float bmx = fmaxf(fmaxf(smx[0][c], smx[1][c]), fmaxf(smx[2][c], smx[3][c]));
            atomicMin(&hdr[c],     __float_as_uint(bmn));
            atomicMax(&hdr[3 + c], __float_as_uint(bmx));
        }
    }
}

__global__ void params_kernel(unsigned* hdr) {
    if (threadIdx.x == 0 && blockIdx.x == 0) {
        int* ip = (int*)(hdr + 8);
        for (int c = 0; c < 3; ++c) {
            float mnf = __uint_as_float(hdr[c]);
            float mxf = __uint_as_float(hdr[3 + c]);
            float delta = mxf - mnf;                        // fp32 sub, like numpy
            int depth = (int)((double)delta / 0.25) + 1 + 4;
            if (depth > kD) depth = kD;
            if (depth < 1) depth = 1;
            ip[c] = depth;
        }
    }
}

// Privatized splat: sy = ((y+8)>>4)+2 partitions rows into bands (8,16,...,16,8),
// so each grid spatial cell (sy,sx) is fed by exactly ONE pixel tile. One
// workgroup per band aggregates into a 512-bucket LDS histogram per channel,
// then writes the cell's full color block with plain coalesced stores — zero
// global atomics.
__global__ void splat_kernel(const float* __restrict__ feat,
                             const float* __restrict__ inp,
                             const unsigned* __restrict__ hdr,
                             float* __restrict__ grid) {
    int bx = blockIdx.x, by = blockIdx.y;          // 65 x 65 bands
    int y0 = (by == 0) ? 0 : 16 * by - 8;
    int x0 = (bx == 0) ? 0 : 16 * bx - 8;
    int h = (by == 0 || by == 64) ? 8 : 16;
    int w = (bx == 0 || bx == 64) ? 8 : 16;

    __shared__ float acc[3 * 512];
    for (int i = threadIdx.x; i < 3 * 512; i += 256) acc[i] = 0.0f;
    __syncthreads();

    int t = threadIdx.x;
    int n = w * h;
    if (t < n) {
        int lx = t & (w - 1);
        int ly = (w == 16) ? (t >> 4) : (t >> 3);
        int y = y0 + ly, x = x0 + lx;
        int p = (y << 10) + x;
        float v0 = feat[p * 3 + 0] - __uint_as_float(hdr[0]);
        float v1 = feat[p * 3 + 1] - __uint_as_float(hdr[1]);
        float v2 = feat[p * 3 + 2] - __uint_as_float(hdr[2]);
        int sr = (int)(v0 * 4.0f + 0.5f) + 2;   // /0.25 == *4 exact
        int sg = (int)(v1 * 4.0f + 0.5f) + 2;
        int sb = (int)(v2 * 4.0f + 0.5f) + 2;
        int ci = (sr << 6) + (sg << 3) + sb;
        atomicAdd(&acc[ci],            inp[p * 3 + 0]);
        atomicAdd(&acc[512 + ci],      inp[p * 3 + 1]);
        atomicAdd(&acc[1024 + ci],     inp[p * 3 + 2]);
    }
    __syncthreads();

    int sy = by + 2, sx = bx + 2;
    long base = ((long)(sy * kSW + sx)) << 9;
    for (int i = threadIdx.x; i < 512; i += 256) {
        grid[base + i]            = acc[i];
        grid[kT3 + base + i]      = acc[512 + i];
        grid[2 * kT3 + base + i]  = acc[1024 + i];
    }
}

// One fused _convn outer-iteration (last-write-wins over axis order y,x,r,g,b;
// see R1 notes). One thread per contiguous 8-cell b-line.
__global__ void blur_fused_kernel(float* __restrict__ dst,
                                  const float* __restrict__ src,
                                  const unsigned* __restrict__ hdr) {
    int line = blockIdx.x * blockDim.x + threadIdx.x;
    if (line >= kLines) return;
    const int* ip = (const int*)(hdr + 8);
    int dr = ip[0], dg = ip[1], db = ip[2];

    int g = line & 7;
    int r = (line >> 3) & 7;
    int rest = line >> 6;           // ch*68*68 + y*68 + x
    int x = rest % 68;
    int yc = rest / 68;             // ch*68 + y
    int y = yc % 68;

    long base = (long)line * 8;
    const float4* s4 = (const float4*)(src + base);
    float4 lo = s4[0], hi = s4[1];
    float v[8] = {lo.x, lo.y, lo.z, lo.w, hi.x, hi.y, hi.z, hi.w};

    bool gInt = (g >= 1) && (g <= dg - 2);
    bool rInt = (r >= 1) && (r <= dr - 2);
    bool xInt = (x >= 1) && (x <= kSW - 2);
    bool yInt = (y >= 1) && (y <= kSH - 2);
    int fs = gInt ? kSG : (rInt ? kSR : (xInt ? kSX : (yInt ? kSY : 0)));

    float out[8];
    bool  wr[8];
    #pragma unroll
    for (int b = 0; b < 8; ++b) {
        if (b >= 1 && b <= db - 2) {
            out[b] = ((v[b - 1] + v[b + 1]) + 2.0f * v[b]) * 0.25f;
            wr[b] = true;
        } else if (fs != 0) {
            out[b] = ((src[base + b - fs] + src[base + b + fs]) + 2.0f * v[b]) * 0.25f;
            wr[b] = true;
        } else {
            out[b] = 0.0f;
            wr[b] = false;
        }
    }
    bool all8 = wr[0] && wr[1] && wr[2] && wr[3] && wr[4] && wr[5] && wr[6] && wr[7];
    if (all8) {
        float4* d4 = (float4*)(dst + base);
        d4[0] = make_float4(out[0], out[1], out[2], out[3]);
        d4[1] = make_float4(out[4], out[5], out[6], out[7]);
    } else {
        #pragma unroll
        for (int b = 0; b < 8; ++b)
            if (wr[b]) dst[base + b] = out[b];
    }
}

__global__ void slice_kernel(const float* __restrict__ feat,
                             const unsigned* __restrict__ hdr,
                             const float* __restrict__ grid,
                             float* __restrict__ out) {
    int p = blockIdx.x * blockDim.x + threadIdx.x;
    if (p >= kHW) return;
    const int* ip = (const int*)(hdr + 8);
    int d3[3] = {ip[0], ip[1], ip[2]};
    int y = p >> 10, x = p & 1023;

    int yi = (y >> 4) + 2;                 // int(y/16 + 2), never clamps (<=65)
    int xi = (x >> 4) + 2;
    float ya = (float)(y & 15) * 0.0625f;  // exact fractional part
    float xa = (float)(x & 15) * 0.0625f;

    int li[3], ri[3];
    float al[3];
    #pragma unroll
    for (int c = 0; c < 3; ++c) {
        float v0 = feat[p * 3 + c] - __uint_as_float(hdr[c]);
        float sv = v0 * 4.0f + 2.0f;
        int l = (int)sv;
        int dm = d3[c] - 1;
        l = l < 0 ? 0 : (l > dm ? dm : l);
        int rr = l + 1 > dm ? dm : l + 1;
        li[c] = l; ri[c] = rr; al[c] = sv - (float)l;
    }

    // spatial part: 4 corners
    int spi[4]; float spw[4];
    {
        int ys[2] = {yi, yi + 1};  float wy[2] = {1.0f - ya, ya};
        int xs[2] = {xi, xi + 1};  float wx[2] = {1.0f - xa, xa};
        #pragma unroll
        for (int cy = 0; cy < 2; ++cy)
        #pragma unroll
        for (int cx = 0; cx < 2; ++cx) {
            spi[cy * 2 + cx] = (ys[cy] * kSW + xs[cx]) << 9;
            spw[cy * 2 + cx] = wy[cy] * wx[cx];
        }
    }
    // color part: 8 corners
    int cpi[8]; float cpw[8];
    {
        int rs[2] = {li[0], ri[0]}; float wrr[2] = {1.0f - al[0], al[0]};
        int gs[2] = {li[1], ri[1]}; float wgg[2] = {1.0f - al[1], al[1]};
        int bs[2] = {li[2], ri[2]}; float wbb[2] = {1.0f - al[2], al[2]};
        #pragma unroll
        for (int cr = 0; cr < 2; ++cr)
        #pragma unroll
        for (int cg = 0; cg < 2; ++cg)
        #pragma unroll
        for (int cb = 0; cb < 2; ++cb) {
            int k = (cr * 2 + cg) * 2 + cb;
            cpi[k] = (rs[cr] << 6) + (gs[cg] << 3) + bs[cb];
            cpw[k] = (wrr[cr] * wgg[cg]) * wbb[cb];
        }
    }

    float acc0 = 0.0f, acc1 = 0.0f, acc2 = 0.0f;
    #pragma unroll
    for (int k = 0; k < 4; ++k) {
        #pragma unroll
        for (int j = 0; j < 8; ++j) {
            int c = spi[k] + cpi[j];
            float w = spw[k] * cpw[j];
            acc0 += w * grid[c];
            acc1 += w * grid[kT3 + c];
            acc2 += w * grid[2 * kT3 + c];
        }
    }
    out[p * 3 + 0] = acc0;
    out[p * 3 + 1] = acc1;
    out[p * 3 + 2] = acc2;
}

}  // namespace

extern "C" void kernel_launch(void* const* d_in, const int* in_sizes, int n_in,
                              void* d_out, int out_size, void* d_ws, size_t ws_size,
                              hipStream_t stream) {
    const float* feat = (const float*)d_in[0];
    const float* inp  = (const float*)d_in[1];
    float* out = (float*)d_out;

    unsigned* hdr = (unsigned*)d_ws;
    float* gridA = (float*)((char*)d_ws + 256);        // splat -> iter2 result
    float* gridB = gridA + 3 * (size_t)kT3;            // iter1 result

    hipMemsetAsync(gridA, 0, 2 * 3 * (size_t)kT3 * sizeof(float), stream);

    init_hdr_kernel<<<1, 64, 0, stream>>>(hdr);
    minmax_kernel<<<256, 256, 0, stream>>>(feat, hdr);
    params_kernel<<<1, 1, 0, stream>>>(hdr);

    splat_kernel<<<dim3(65, 65), 256, 0, stream>>>(feat, inp, hdr, gridA);

    int blurBlocks = (kLines + 255) / 256;
    // _convn outer iter 1: src = gridA (splat), dst = gridB (zeros)
    blur_fused_kernel<<<blurBlocks, 256, 0, stream>>>(gridB, gridA, hdr);
    // _convn outer iter 2: src = gridB, dst = gridA (holds original splat = `data`)
    blur_fused_kernel<<<blurBlocks, 256, 0, stream>>>(gridA, gridB, hdr);

    slice_kernel<<<(kHW + 255) / 256, 256, 0, stream>>>(feat, hdr, gridA, out);
}

// Round 4
// 161.246 us; speedup vs baseline: 4.7773x; 1.5019x over previous
//
#include <hip/hip_runtime.h>

namespace {

constexpr int kH  = 1024;
constexpr int kW  = 1024;
constexpr int kHW = kH * kW;
constexpr int kSH = 68;           // int(1023/16)+1+2*2
constexpr int kSW = 68;
constexpr int kD  = 8;            // max depth; features uniform [0,1) -> depth <= 8
constexpr int kT3 = kSH * kSW * kD * kD * kD;   // 2,367,488 cells per channel
// fixed strides (floats) inside one channel grid [68][68][8][8][8]
constexpr int kSG = 8;
constexpr int kSR = 64;
constexpr int kSX = 512;
constexpr int kSY = 512 * 68;     // 34816
constexpr int kLines = 3 * kSH * kSW * kD * kD; // 887,808 b-lines of 8 cells

// ---- header layout in d_ws (uint words) ----
// [0..2] min bits per channel   [3..5] max bits per channel
// [8] dr [9] dg [10] db

__global__ void init_hdr_kernel(unsigned* hdr) {
    int t = threadIdx.x;
    if (t < 3) hdr[t] = 0x7f800000u;      // +inf (values >= 0, bit order == value order)
    else if (t < 6) hdr[t] = 0u;
}

__global__ void minmax_kernel(const float* __restrict__ feat, unsigned* hdr) {
    float mn[3] = {1e30f, 1e30f, 1e30f};
    float mx[3] = {-1e30f, -1e30f, -1e30f};
    int tid = blockIdx.x * blockDim.x + threadIdx.x;
    int stride = gridDim.x * blockDim.x;
    for (int p = tid; p < kHW; p += stride) {
        #pragma unroll
        for (int c = 0; c < 3; ++c) {
            float v = feat[p * 3 + c];
            mn[c] = fminf(mn[c], v);
            mx[c] = fmaxf(mx[c], v);
        }
    }
    #pragma unroll
    for (int off = 32; off > 0; off >>= 1) {
        #pragma unroll
        for (int c = 0; c < 3; ++c) {
            mn[c] = fminf(mn[c], __shfl_down(mn[c], off, 64));
            mx[c] = fmaxf(mx[c], __shfl_down(mx[c], off, 64));
        }
    }
    __shared__ float smn[4][3], smx[4][3];
    int wave = threadIdx.x >> 6;
    if ((threadIdx.x & 63) == 0) {
        #pragma unroll
        for (int c = 0; c < 3; ++c) { smn[wave][c] = mn[c]; smx[wave][c] = mx[c]; }
    }
    __syncthreads();
    if (threadIdx.x == 0) {
        #pragma unroll
        for (int c = 0; c < 3; ++c) {
            float bmn = fminf(fminf(smn[0][c], smn[1][c]), fminf(smn[2][c], smn[3][c]));
            float bmx = fmaxf(fmaxf(smx[0][c], smx[1][c]), fmaxf(smx[2][c], smx[3][c]));
            atomicMin(&hdr[c],     __float_as_uint(bmn));
            atomicMax(&hdr[3 + c], __float_as_uint(bmx));
        }
    }
}

__global__ void params_kernel(unsigned* hdr) {
    if (threadIdx.x == 0 && blockIdx.x == 0) {
        int* ip = (int*)(hdr + 8);
        for (int c = 0; c < 3; ++c) {
            float mnf = __uint_as_float(hdr[c]);
            float mxf = __uint_as_float(hdr[3 + c]);
            float delta = mxf - mnf;                        // fp32 sub, like numpy
            int depth = (int)((double)delta / 0.25) + 1 + 4;
            if (depth > kD) depth = kD;
            if (depth < 1) depth = 1;
            ip[c] = depth;
        }
    }
}

// Privatized splat over the FULL 68x68 cell grid (no memset needed):
// boundary cells (sy<2 || sy>66 || sx<2 || sx>66) get zeros; each interior
// cell is fed by exactly one pixel band -> LDS histogram, coalesced stores,
// zero global atomics.
__global__ void splat_kernel(const float* __restrict__ feat,
                             const float* __restrict__ inp,
                             const unsigned* __restrict__ hdr,
                             float* __restrict__ grid) {
    int bx = blockIdx.x, by = blockIdx.y;          // 68 x 68 cells
    long base = ((long)(by * kSW + bx)) << 9;
    bool boundary = (by < 2) || (by > 66) || (bx < 2) || (bx > 66);
    if (boundary) {
        float4 z = make_float4(0.f, 0.f, 0.f, 0.f);
        float4* d0 = (float4*)(grid + base);
        float4* d1 = (float4*)(grid + kT3 + base);
        float4* d2 = (float4*)(grid + 2 * kT3 + base);
        for (int i = threadIdx.x; i < 128; i += 256) { d0[i] = z; d1[i] = z; d2[i] = z; }
        return;
    }
    int iy = by - 2, ix = bx - 2;                  // band index 0..64
    int y0 = (iy == 0) ? 0 : 16 * iy - 8;
    int x0 = (ix == 0) ? 0 : 16 * ix - 8;
    int h = (iy == 0 || iy == 64) ? 8 : 16;
    int w = (ix == 0 || ix == 64) ? 8 : 16;

    __shared__ float acc[3 * 512];
    for (int i = threadIdx.x; i < 3 * 512; i += 256) acc[i] = 0.0f;
    __syncthreads();

    int t = threadIdx.x;
    int n = w * h;
    if (t < n) {
        int lx = t & (w - 1);
        int ly = (w == 16) ? (t >> 4) : (t >> 3);
        int y = y0 + ly, x = x0 + lx;
        int p = (y << 10) + x;
        float v0 = feat[p * 3 + 0] - __uint_as_float(hdr[0]);
        float v1 = feat[p * 3 + 1] - __uint_as_float(hdr[1]);
        float v2 = feat[p * 3 + 2] - __uint_as_float(hdr[2]);
        int sr = (int)(v0 * 4.0f + 0.5f) + 2;   // /0.25 == *4 exact
        int sg = (int)(v1 * 4.0f + 0.5f) + 2;
        int sb = (int)(v2 * 4.0f + 0.5f) + 2;
        int ci = (sr << 6) + (sg << 3) + sb;
        atomicAdd(&acc[ci],            inp[p * 3 + 0]);
        atomicAdd(&acc[512 + ci],      inp[p * 3 + 1]);
        atomicAdd(&acc[1024 + ci],     inp[p * 3 + 2]);
    }
    __syncthreads();

    for (int i = threadIdx.x; i < 512; i += 256) {
        grid[base + i]            = acc[i];
        grid[kT3 + base + i]      = acc[512 + i];
        grid[2 * kT3 + base + i]  = acc[1024 + i];
    }
}

// One fused _convn outer-iteration (last-write-wins over axis order y,x,r,g,b).
// ZeroFill=true (iter1): cells with no applicable axis get 0 (reference data
// starts as zeros) -> every cell written, uniform float4 stores, and dst needs
// no pre-zeroing. ZeroFill=false (iter2): those cells retain dst's prior value
// (the original splat).
template <bool ZeroFill>
__global__ void blur_fused_kernel(float* __restrict__ dst,
                                  const float* __restrict__ src,
                                  const unsigned* __restrict__ hdr) {
    int line = blockIdx.x * blockDim.x + threadIdx.x;
    if (line >= kLines) return;
    const int* ip = (const int*)(hdr + 8);
    int dr = ip[0], dg = ip[1], db = ip[2];

    int g = line & 7;
    int r = (line >> 3) & 7;
    int rest = line >> 6;           // ch*68*68 + y*68 + x
    int x = rest % 68;
    int yc = rest / 68;             // ch*68 + y
    int y = yc % 68;

    long base = (long)line * 8;
    const float4* s4 = (const float4*)(src + base);
    float4 lo = s4[0], hi = s4[1];
    float v[8] = {lo.x, lo.y, lo.z, lo.w, hi.x, hi.y, hi.z, hi.w};

    bool gInt = (g >= 1) && (g <= dg - 2);
    bool rInt = (r >= 1) && (r <= dr - 2);
    bool xInt = (x >= 1) && (x <= kSW - 2);
    bool yInt = (y >= 1) && (y <= kSH - 2);
    int fs = gInt ? kSG : (rInt ? kSR : (xInt ? kSX : (yInt ? kSY : 0)));

    float nm[8], np[8];
    if (fs != 0) {
        const float4* m4 = (const float4*)(src + base - fs);   // fs multiple of 4
        const float4* p4 = (const float4*)(src + base + fs);
        float4 a = m4[0], b4 = m4[1], c = p4[0], d = p4[1];
        nm[0]=a.x; nm[1]=a.y; nm[2]=a.z; nm[3]=a.w; nm[4]=b4.x; nm[5]=b4.y; nm[6]=b4.z; nm[7]=b4.w;
        np[0]=c.x; np[1]=c.y; np[2]=c.z; np[3]=c.w; np[4]=d.x; np[5]=d.y; np[6]=d.z; np[7]=d.w;
    }

    float out[8];
    bool  wr[8];
    #pragma unroll
    for (int b = 0; b < 8; ++b) {
        if (b >= 1 && b <= db - 2) {
            out[b] = ((v[b - 1] + v[b + 1]) + 2.0f * v[b]) * 0.25f;
            wr[b] = true;
        } else if (fs != 0) {
            out[b] = ((nm[b] + np[b]) + 2.0f * v[b]) * 0.25f;
            wr[b] = true;
        } else {
            out[b] = 0.0f;
            wr[b] = ZeroFill;
        }
    }
    bool all8 = ZeroFill ||
        (wr[0] && wr[1] && wr[2] && wr[3] && wr[4] && wr[5] && wr[6] && wr[7]);
    if (all8) {
        float4* d4 = (float4*)(dst + base);
        d4[0] = make_float4(out[0], out[1], out[2], out[3]);
        d4[1] = make_float4(out[4], out[5], out[6], out[7]);
    } else {
        #pragma unroll
        for (int b = 0; b < 8; ++b)
            if (wr[b]) dst[base + b] = out[b];
    }
}

// LDS-staged slice: one workgroup per 16x16 pixel tile. All 256 pixels share
// spatial cells (ty+2..ty+3, tx+2..tx+3) -> stage 4 cells x 512 colors x 3 ch
// (24 KB) with coalesced float4 loads, then gather penta-linear corners from
// LDS instead of scattering 96 loads/pixel into L2.
__global__ __launch_bounds__(256) void slice_kernel(const float* __restrict__ feat,
                                                    const unsigned* __restrict__ hdr,
                                                    const float* __restrict__ grid,
                                                    float* __restrict__ out) {
    __shared__ float sg[3 * 4 * 512];   // [ch][cell][512]
    int tx = blockIdx.x, ty = blockIdx.y;   // 64 x 64 tiles

    {
        const float4* g4 = (const float4*)grid;
        float4* s4 = (float4*)sg;
        #pragma unroll
        for (int it = 0; it < 2; ++it) {
            int i = threadIdx.x + it * 256;       // float4 index within a channel plane [0,512)
            int cell = i >> 7;                    // 0..3 = (dy<<1)|dx
            int ci4 = i & 127;
            int cy = ty + 2 + (cell >> 1), cx = tx + 2 + (cell & 1);
            long cbase4 = ((long)(cy * kSW + cx)) << 7;   // 128 float4 per cell
            #pragma unroll
            for (int ch = 0; ch < 3; ++ch)
                s4[ch * 512 + i] = g4[(long)ch * (kT3 / 4) + cbase4 + ci4];
        }
    }
    __syncthreads();

    const int* ip = (const int*)(hdr + 8);
    int d3[3] = {ip[0], ip[1], ip[2]};
    int lx = threadIdx.x & 15, ly = threadIdx.x >> 4;
    int y = (ty << 4) + ly, x = (tx << 4) + lx;
    int p = (y << 10) + x;

    float ya = (float)ly * 0.0625f;   // exact fractional part of y/16
    float xa = (float)lx * 0.0625f;

    int li[3], ri[3];
    float al[3];
    #pragma unroll
    for (int c = 0; c < 3; ++c) {
        float v0 = feat[p * 3 + c] - __uint_as_float(hdr[c]);
        float sv = v0 * 4.0f + 2.0f;
        int l = (int)sv;
        int dm = d3[c] - 1;
        l = l < 0 ? 0 : (l > dm ? dm : l);
        int rr = l + 1 > dm ? dm : l + 1;
        li[c] = l; ri[c] = rr; al[c] = sv - (float)l;
    }

    float spw[4];
    {
        float wy[2] = {1.0f - ya, ya};
        float wx[2] = {1.0f - xa, xa};
        spw[0] = wy[0] * wx[0]; spw[1] = wy[0] * wx[1];
        spw[2] = wy[1] * wx[0]; spw[3] = wy[1] * wx[1];
    }
    int cpi[8]; float cpw[8];
    {
        int rs[2] = {li[0], ri[0]}; float wrr[2] = {1.0f - al[0], al[0]};
        int gs[2] = {li[1], ri[1]}; float wgg[2] = {1.0f - al[1], al[1]};
        int bs[2] = {li[2], ri[2]}; float wbb[2] = {1.0f - al[2], al[2]};
        #pragma unroll
        for (int cr = 0; cr < 2; ++cr)
        #pragma unroll
        for (int cg = 0; cg < 2; ++cg)
        #pragma unroll
        for (int cb = 0; cb < 2; ++cb) {
            int k = (cr * 2 + cg) * 2 + cb;
            cpi[k] = (rs[cr] << 6) + (gs[cg] << 3) + bs[cb];
            cpw[k] = (wrr[cr] * wgg[cg]) * wbb[cb];
        }
    }

    float acc0 = 0.0f, acc1 = 0.0f, acc2 = 0.0f;
    #pragma unroll
    for (int k = 0; k < 4; ++k) {
        #pragma unroll
        for (int j = 0; j < 8; ++j) {
            int si = (k << 9) + cpi[j];
            float w = spw[k] * cpw[j];
            acc0 += w * sg[si];
            acc1 += w * sg[2048 + si];
            acc2 += w * sg[4096 + si];
        }
    }
    out[p * 3 + 0] = acc0;
    out[p * 3 + 1] = acc1;
    out[p * 3 + 2] = acc2;
}

}  // namespace

extern "C" void kernel_launch(void* const* d_in, const int* in_sizes, int n_in,
                              void* d_out, int out_size, void* d_ws, size_t ws_size,
                              hipStream_t stream) {
    const float* feat = (const float*)d_in[0];
    const float* inp  = (const float*)d_in[1];
    float* out = (float*)d_out;

    unsigned* hdr = (unsigned*)d_ws;
    float* gridA = (float*)((char*)d_ws + 256);        // splat -> iter2 result
    float* gridB = gridA + 3 * (size_t)kT3;            // iter1 result

    init_hdr_kernel<<<1, 64, 0, stream>>>(hdr);
    minmax_kernel<<<256, 256, 0, stream>>>(feat, hdr);
    params_kernel<<<1, 1, 0, stream>>>(hdr);

    splat_kernel<<<dim3(68, 68), 256, 0, stream>>>(feat, inp, hdr, gridA);

    int blurBlocks = (kLines + 255) / 256;
    // _convn outer iter 1: src = gridA (splat), dst = gridB (zero-filled by kernel)
    blur_fused_kernel<true><<<blurBlocks, 256, 0, stream>>>(gridB, gridA, hdr);
    // _convn outer iter 2: src = gridB, dst = gridA (holds original splat = `data`)
    blur_fused_kernel<false><<<blurBlocks, 256, 0, stream>>>(gridA, gridB, hdr);

    slice_kernel<<<dim3(64, 64), 256, 0, stream>>>(feat, hdr, gridA, out);
}